// Round 11
// baseline (221.878 us; speedup 1.0000x reference)
//
#include <hip/hip_runtime.h>

// BilinearMixture. R2-R9 factorial: time pinned ~101-107us while bytes (R5),
// L2-miss locality (R6), instruction count (R9), and MLP (R9) each varied 2x.
// Sole invariant: ~4 random cache-line LOOKUPS per edge (u-row, v-row,
// u_bias, v_bias). R10: pack int8 features (64B, R5-proven accuracy) + 5 fp32
// biases + replicated fp32 scale into ONE 128B row -> 2 lookups/edge.
// Row layout (16 lanes x 8B): lanes 0-7 = 64 int8 feats; lane 8+c =
// {bias[c], scale}; lanes 13-15 zero-padded (full-line write in pack pass).

#define ROWB 128

template <int CTRL>
__device__ __forceinline__ float dpp_add(float x) {
    int t = __builtin_amdgcn_update_dpp(0, __float_as_int(x), CTRL, 0xF, 0xF, true);
    return x + __int_as_float(t);
}
template <int CTRL>
__device__ __forceinline__ float dpp_max(float x) {
    int t = __builtin_amdgcn_update_dpp(0, __float_as_int(x), CTRL, 0xF, 0xF, true);
    return fmaxf(x, __int_as_float(t));
}
// Sum (a,b,c) over each 16-lane group: xor1, xor2 (quad_perm), ror4, ror8.
// Butterfly -> every lane ends with the full 16-lane sum.
__device__ __forceinline__ void reduce16_3(float& a, float& b, float& c) {
    a = dpp_add<0xB1>(a);  b = dpp_add<0xB1>(b);  c = dpp_add<0xB1>(c);
    a = dpp_add<0x4E>(a);  b = dpp_add<0x4E>(b);  c = dpp_add<0x4E>(c);
    a = dpp_add<0x124>(a); b = dpp_add<0x124>(b); c = dpp_add<0x124>(c);
    a = dpp_add<0x128>(a); b = dpp_add<0x128>(b); c = dpp_add<0x128>(c);
}
__device__ __forceinline__ float reduce16_max(float x) {
    x = dpp_max<0xB1>(x); x = dpp_max<0x4E>(x);
    x = dpp_max<0x124>(x); x = dpp_max<0x128>(x);
    return x;
}

__device__ __forceinline__ void unpack4i8(int t, float* f) {
    f[0] = (float)((t << 24) >> 24);
    f[1] = (float)((t << 16) >> 24);
    f[2] = (float)((t <<  8) >> 24);
    f[3] = (float)( t        >> 24);
}

// ---------- pack pass: one 16-lane group per row ----------
__global__ __launch_bounds__(256) void pack_rows(
    const float* __restrict__ u_feat, const float* __restrict__ v_feat,
    const float* __restrict__ u_bias, const float* __restrict__ v_bias,
    char* __restrict__ u_p, char* __restrict__ v_p, int nru, int nrv)
{
    const int tid   = blockIdx.x * blockDim.x + threadIdx.x;
    const int sl    = threadIdx.x & 15;
    const int group = tid >> 4;
    const int ng    = (gridDim.x * blockDim.x) >> 4;
    const int ntot  = nru + nrv;

    for (int r = group; r < ntot; r += ng) {
        const bool isU = (r < nru);
        const int  rr  = isU ? r : r - nru;
        const float* src = (isU ? u_feat : v_feat) + (size_t)rr * 64;

        float x[8];
        float am = 0.f;
        if (sl < 8) {
            const float4 a = *reinterpret_cast<const float4*>(src + sl * 8);
            const float4 b = *reinterpret_cast<const float4*>(src + sl * 8 + 4);
            x[0]=a.x; x[1]=a.y; x[2]=a.z; x[3]=a.w;
            x[4]=b.x; x[5]=b.y; x[6]=b.z; x[7]=b.w;
            #pragma unroll
            for (int j = 0; j < 8; ++j) am = fmaxf(am, fabsf(x[j]));
        }
        am = reduce16_max(am);
        am = fmaxf(am, 1e-20f);
        const float inv   = 127.0f / am;
        const float scale = am / 127.0f;

        char* row = (isU ? u_p : v_p) + (size_t)rr * ROWB;
        if (sl < 8) {
            int b[8];
            #pragma unroll
            for (int j = 0; j < 8; ++j) b[j] = (int)rintf(x[j] * inv) & 255;
            const int lo = b[0] | (b[1] << 8) | (b[2] << 16) | (b[3] << 24);
            const int hi = b[4] | (b[5] << 8) | (b[6] << 16) | (b[7] << 24);
            reinterpret_cast<int2*>(row)[sl] = make_int2(lo, hi);
        } else if (sl < 13) {
            const int   cc = sl - 8;
            const float bb = (isU ? u_bias : v_bias)[(size_t)rr * 5 + cc];
            reinterpret_cast<float2*>(row)[sl] = make_float2(bb, scale);
        } else {
            reinterpret_cast<float2*>(row)[sl] = make_float2(0.f, 0.f);
        }
    }
}

// ---------- main: 2 lookups/edge, 16 lanes/edge, 2-edge ILP ----------
__global__ __launch_bounds__(256) void bilinear_packed(
    const char* __restrict__ u_p, const char* __restrict__ v_p,
    const float* __restrict__ W, const float* __restrict__ scalars,
    const int* __restrict__ u_idx, const int* __restrict__ v_idx,
    float* __restrict__ out, int E)
{
    const int tid    = blockIdx.x * blockDim.x + threadIdx.x;
    const int sl     = threadIdx.x & 15;
    const int group  = tid >> 4;
    const int ngroup = (gridDim.x * blockDim.x) >> 4;
    const int step   = ngroup * 2;

    const bool lead   = (sl < 8);        // dot lanes: own d = sl*8..sl*8+7
    const bool writer = (sl >= 8) && (sl < 13);
    const int  c      = sl - 8;

    float w0[8], w1[8], w2[8];
    #pragma unroll
    for (int j = 0; j < 8; ++j) { w0[j] = 0.f; w1[j] = 0.f; w2[j] = 0.f; }
    if (lead) {
        const int d0 = sl * 8;
        #pragma unroll
        for (int j = 0; j < 8; ++j) {
            w0[j] = W[d0 + j];
            w1[j] = W[64 + d0 + j];
            w2[j] = W[128 + d0 + j];
        }
    }
    float s0 = 0.f, s1 = 0.f, s2 = 0.f;
    if (writer) { s0 = scalars[c]; s1 = scalars[5 + c]; s2 = scalars[10 + c]; }

    int e0 = group * 2;
    if (e0 >= E) return;

    int uu0 = u_idx[e0];
    int vv0 = v_idx[e0];
    int uu1 = (e0 + 1 < E) ? u_idx[e0 + 1] : uu0;
    int vv1 = (e0 + 1 < E) ? v_idx[e0 + 1] : vv0;

    for (; e0 < E; e0 += step) {
        const int  e1   = e0 + 1;
        const bool has1 = (e1 < E);
        const int cu0 = uu0, cv0 = vv0, cu1 = uu1, cv1 = vv1;

        // THE only random lookups: one 128B row per table per edge.
        const int2 Ua = *reinterpret_cast<const int2*>(u_p + (size_t)cu0 * ROWB + sl * 8);
        const int2 Va = *reinterpret_cast<const int2*>(v_p + (size_t)cv0 * ROWB + sl * 8);
        const int2 Ub = *reinterpret_cast<const int2*>(u_p + (size_t)cu1 * ROWB + sl * 8);
        const int2 Vb = *reinterpret_cast<const int2*>(v_p + (size_t)cv1 * ROWB + sl * 8);

        // Prefetch next iteration's indices (sequential, L2-friendly).
        const int nb = e0 + step;
        if (nb < E) {
            uu0 = u_idx[nb];
            vv0 = v_idx[nb];
            const int nb1 = nb + 1;
            uu1 = (nb1 < E) ? u_idx[nb1] : uu0;
            vv1 = (nb1 < E) ? v_idx[nb1] : vv0;
        }

        float qa0 = 0.f, qa1 = 0.f, qa2 = 0.f;
        float qb0 = 0.f, qb1 = 0.f, qb2 = 0.f;
        if (lead) {
            float fu[8], fv[8];
            unpack4i8(Ua.x, fu); unpack4i8(Ua.y, fu + 4);
            unpack4i8(Va.x, fv); unpack4i8(Va.y, fv + 4);
            #pragma unroll
            for (int j = 0; j < 8; ++j) {
                const float p = fu[j] * fv[j];
                qa0 += p * w0[j]; qa1 += p * w1[j]; qa2 += p * w2[j];
            }
            unpack4i8(Ub.x, fu); unpack4i8(Ub.y, fu + 4);
            unpack4i8(Vb.x, fv); unpack4i8(Vb.y, fv + 4);
            #pragma unroll
            for (int j = 0; j < 8; ++j) {
                const float p = fu[j] * fv[j];
                qb0 += p * w0[j]; qb1 += p * w1[j]; qb2 += p * w2[j];
            }
        }

        reduce16_3(qa0, qa1, qa2);
        reduce16_3(qb0, qb1, qb2);

        if (writer) {
            // Lane 8+c's own gather slot = {bias[c], scale} for each row.
            const float bu0 = __int_as_float(Ua.x), su0 = __int_as_float(Ua.y);
            const float bv0 = __int_as_float(Va.x), sv0 = __int_as_float(Va.y);
            out[(size_t)e0 * 5 + c] =
                (qa0 * s0 + qa1 * s1 + qa2 * s2) * (su0 * sv0) + bu0 + bv0;
            if (has1) {
                const float bu1 = __int_as_float(Ub.x), su1 = __int_as_float(Ub.y);
                const float bv1 = __int_as_float(Vb.x), sv1 = __int_as_float(Vb.y);
                out[(size_t)e1 * 5 + c] =
                    (qb0 * s0 + qb1 * s1 + qb2 * s2) * (su1 * sv1) + bu1 + bv1;
            }
        }
    }
}

// ---------- fallback: direct fp32 (only if ws too small; normally unused) ---
__global__ __launch_bounds__(256) void bilinear_edges_f32(
    const float* __restrict__ u_feat, const float* __restrict__ v_feat,
    const float* __restrict__ W, const float* __restrict__ scalars,
    const float* __restrict__ u_bias, const float* __restrict__ v_bias,
    const int* __restrict__ u_idx, const int* __restrict__ v_idx,
    float* __restrict__ out, int E)
{
    const int tid    = blockIdx.x * blockDim.x + threadIdx.x;
    const int sl     = threadIdx.x & 15;
    const int group  = tid >> 4;
    const int ngroup = (gridDim.x * blockDim.x) >> 4;

    const int d0 = sl * 4;
    float w0[4], w1[4], w2[4];
    #pragma unroll
    for (int t = 0; t < 4; ++t) {
        w0[t] = W[0 * 64 + d0 + t];
        w1[t] = W[1 * 64 + d0 + t];
        w2[t] = W[2 * 64 + d0 + t];
    }
    float s0 = 0.f, s1 = 0.f, s2 = 0.f;
    if (sl < 5) { s0 = scalars[sl]; s1 = scalars[5 + sl]; s2 = scalars[10 + sl]; }

    for (int e = group; e < E; e += ngroup) {
        const int uu = u_idx[e];
        const int vv = v_idx[e];
        const float4 u4 = *reinterpret_cast<const float4*>(u_feat + (size_t)uu * 64 + d0);
        const float4 v4 = *reinterpret_cast<const float4*>(v_feat + (size_t)vv * 64 + d0);
        float ubx = 0.f, vbx = 0.f;
        if (sl < 5) { ubx = u_bias[(size_t)uu * 5 + sl]; vbx = v_bias[(size_t)vv * 5 + sl]; }

        const float p0 = u4.x * v4.x, p1 = u4.y * v4.y,
                    p2 = u4.z * v4.z, p3 = u4.w * v4.w;
        float q0 = p0*w0[0] + p1*w0[1] + p2*w0[2] + p3*w0[3];
        float q1 = p0*w1[0] + p1*w1[1] + p2*w1[2] + p3*w1[3];
        float q2 = p0*w2[0] + p1*w2[1] + p2*w2[2] + p3*w2[3];
        reduce16_3(q0, q1, q2);
        if (sl < 5)
            out[(size_t)e * 5 + sl] = q0 * s0 + q1 * s1 + q2 * s2 + ubx + vbx;
    }
}

extern "C" void kernel_launch(void* const* d_in, const int* in_sizes, int n_in,
                              void* d_out, int out_size, void* d_ws, size_t ws_size,
                              hipStream_t stream) {
    const float* u_feat  = (const float*)d_in[0];
    const float* v_feat  = (const float*)d_in[1];
    const float* W       = (const float*)d_in[2];
    const float* scalars = (const float*)d_in[3];
    const float* u_bias  = (const float*)d_in[4];
    const float* v_bias  = (const float*)d_in[5];
    const int*   u_idx   = (const int*)d_in[6];
    const int*   v_idx   = (const int*)d_in[7];
    float*       out     = (float*)d_out;

    const int nu = in_sizes[0];          // NUM_USERS * 64
    const int nv = in_sizes[1];          // NUM_ITEMS * 64
    const int E  = in_sizes[6];          // 2,000,000 edges
    const int nru = nu / 64;
    const int nrv = nv / 64;

    const size_t ws_need = (size_t)(nru + nrv) * ROWB;

    if (ws_size >= ws_need) {
        char* u_p = (char*)d_ws;
        char* v_p = u_p + (size_t)nru * ROWB;
        pack_rows<<<2048, 256, 0, stream>>>(
            u_feat, v_feat, u_bias, v_bias, u_p, v_p, nru, nrv);
        bilinear_packed<<<2048, 256, 0, stream>>>(
            u_p, v_p, W, scalars, u_idx, v_idx, out, E);
    } else {
        bilinear_edges_f32<<<2048, 256, 0, stream>>>(
            u_feat, v_feat, W, scalars, u_bias, v_bias, u_idx, v_idx, out, E);
    }
}